// Round 13
// baseline (374.317 us; speedup 1.0000x reference)
//
#include <hip/hip_runtime.h>
#include <math.h>

#define HW 25600
#define IMGW 160
#define CDIM 256
#define NB 4
#define NHEADS 8
#define SZB ((long)CDIM * HW)   // 6,553,600 elems

typedef __attribute__((ext_vector_type(8))) short short8v;
typedef __attribute__((ext_vector_type(4))) float f32x4;
typedef __attribute__((ext_vector_type(8))) unsigned short us8;

union FragU {
    us8 o;
    short8v s;
    unsigned u32[4];
};

__device__ inline unsigned short f2bf(float f) {
    unsigned u = __float_as_uint(f);
    return (unsigned short)((u + 0x7fffu + ((u >> 16) & 1u)) >> 16);
}
__device__ inline float bf2f(unsigned short h) {
    return __uint_as_float(((unsigned)h) << 16);
}

// ---------------------------------------------------------------------------
// all weights fp32 -> PLAIN bf16 [co][256], one dispatch. grid(96)
// covers kv_w (131072) then q_w (65536) elems, 8/thread.
// ---------------------------------------------------------------------------
__global__ __launch_bounds__(256) void cvtw_k(
    const float* __restrict__ kv_w, const float* __restrict__ q_w,
    unsigned short* __restrict__ wkv, unsigned short* __restrict__ wq)
{
    long i = ((long)blockIdx.x * 256 + threadIdx.x) * 8;
    const float* src;
    unsigned short* dst;
    if (i < 131072) { src = kv_w + i; dst = wkv + i; }
    else            { src = q_w + (i - 131072); dst = wq + (i - 131072); }
    float4 v0 = *(const float4*)src;
    float4 v1 = *(const float4*)(src + 4);
    us8 o;
    o[0] = f2bf(v0.x); o[1] = f2bf(v0.y); o[2] = f2bf(v0.z); o[3] = f2bf(v0.w);
    o[4] = f2bf(v1.x); o[5] = f2bf(v1.y); o[6] = f2bf(v1.z); o[7] = f2bf(v1.w);
    *(us8*)dst = o;
}

// ---------------------------------------------------------------------------
// bf16 MFMA GEMM v5 -- barrier-free (gram_k pattern at scale):
// out[b][co][n] = sum_k W[co][k] * X[k][n],  K = 256 (8 kt-steps).
// NO LDS staging, NO barriers in the K-loop. Fragments loaded directly from
// global (L2-resident via XCD swizzle):
//   A: 4 x us8 contiguous 16B from plain W[co][256].
//   B (XF32=1): 32 scalar fp32 (coalesced 64B segs) + cvt_pk in registers.
//   B (XF32=0): 4 x us8 contiguous 16B from plain-transposed XT[n][256].
// LDS used only for the coalesced C-epilogue bounce.
// XCD-bijective block swizzle. Requires (gridDim.x*gridDim.y) % 8 == 0.
// ---------------------------------------------------------------------------
template<int OUTF32, int XF32>
__global__ __launch_bounds__(256) void gemm5_k(
    const void* __restrict__ Xv, const unsigned short* __restrict__ W,
    void* __restrict__ outp, long xbs, long wbs, long obs)
{
    __shared__ __align__(16) char SMEM[34816];
    const int t  = threadIdx.x;
    const int l  = t & 63;
    const int wv = t >> 6;
    const int g  = l >> 4;
    const int ln = l & 15;

    // XCD-aware bijective swizzle (nwg % 8 == 0)
    const int NX = gridDim.x;
    const int orig = blockIdx.y * NX + blockIdx.x;
    const int chunkp = (NX * gridDim.y) >> 3;
    const int wgid = (orig & 7) * chunkp + (orig >> 3);
    const int co0 = (wgid % NX) * 128;
    const int n0  = (wgid / NX) * 128;

    const long b  = blockIdx.z;
    const unsigned short* Wb  = W + b * wbs;
    const float* Xfp          = (const float*)Xv + b * xbs;
    const unsigned short* Xbf = (const unsigned short*)Xv + b * xbs;
    const int wr = wv >> 1, wc = wv & 1;
    const int arow0 = co0 + wr * 64 + ln;   // + i*16
    const int bcol0 = n0 + wc * 64 + ln;    // + j*16

    f32x4 acc[4][4];
#pragma unroll
    for (int i = 0; i < 4; ++i)
#pragma unroll
        for (int j = 0; j < 4; ++j) acc[i][j] = (f32x4){0.f, 0.f, 0.f, 0.f};

    for (int kt = 0; kt < 8; ++kt) {
        const int kb = kt * 32 + g * 8;
        FragU A_[4], B_[4];
#pragma unroll
        for (int i = 0; i < 4; ++i)
            A_[i].o = *(const us8*)&Wb[(long)(arow0 + i * 16) * CDIM + kb];
        if (XF32) {
#pragma unroll
            for (int j = 0; j < 4; ++j) {
                float f[8];
#pragma unroll
                for (int u = 0; u < 8; ++u)
                    f[u] = Xfp[(long)(kb + u) * HW + bcol0 + j * 16];
#pragma unroll
                for (int e2 = 0; e2 < 4; ++e2) {
                    unsigned rr;
                    asm("v_cvt_pk_bf16_f32 %0, %1, %2"
                        : "=v"(rr) : "v"(f[e2 * 2]), "v"(f[e2 * 2 + 1]));
                    B_[j].u32[e2] = rr;
                }
            }
        } else {
#pragma unroll
            for (int j = 0; j < 4; ++j)
                B_[j].o = *(const us8*)&Xbf[(long)(bcol0 + j * 16) * CDIM + kb];
        }
#pragma unroll
        for (int i = 0; i < 4; ++i)
#pragma unroll
            for (int j = 0; j < 4; ++j)
                acc[i][j] = __builtin_amdgcn_mfma_f32_16x16x32_bf16(
                    A_[i].s, B_[j].s, acc[i][j], 0, 0, 0);
    }

    // ---- coalesced epilogue via LDS bounce
    // D layout: col=lane&15, row=(lane>>4)*4+reg (HW-verified)
    if (OUTF32) {
        float* ef = (float*)SMEM;   // [64][132] fp32, 33792 B
        float* ob = (float*)outp + b * obs;
#pragma unroll
        for (int h2 = 0; h2 < 2; ++h2) {
            if (wr == h2) {
#pragma unroll
                for (int i = 0; i < 4; ++i)
#pragma unroll
                    for (int j = 0; j < 4; ++j)
#pragma unroll
                        for (int r = 0; r < 4; ++r)
                            ef[(i * 16 + g * 4 + r) * 132 + wc * 64 + j * 16 + ln]
                                = acc[i][j][r];
            }
            __syncthreads();
#pragma unroll
            for (int p = 0; p < 8; ++p) {
                int idx = p * 256 + t;         // 2048 float4 chunks
                int row = idx >> 5;
                int c4 = (idx & 31) * 4;
                float4 v = *(const float4*)&ef[row * 132 + c4];
                *(float4*)(ob + (long)(co0 + h2 * 64 + row) * HW + n0 + c4) = v;
            }
            __syncthreads();
        }
    } else {
        unsigned short* eb = (unsigned short*)SMEM;  // [128][136] bf16, 34816 B
        unsigned short* ob = (unsigned short*)outp + b * obs;
#pragma unroll
        for (int i = 0; i < 4; ++i)
#pragma unroll
            for (int j = 0; j < 4; ++j)
#pragma unroll
                for (int r = 0; r < 4; ++r)
                    eb[(wr * 64 + i * 16 + g * 4 + r) * 136 + wc * 64 + j * 16 + ln]
                        = f2bf(acc[i][j][r]);
        __syncthreads();
#pragma unroll
        for (int p = 0; p < 8; ++p) {
            int idx = p * 256 + t;              // 2048 us8 chunks
            int row = idx >> 4;
            int c8 = (idx & 15) * 8;
            us8 v = *(const us8*)&eb[row * 136 + c8];
            *(us8*)(ob + (long)(co0 + row) * HW + n0 + c8) = v;
        }
    }
}

// ---------------------------------------------------------------------------
// depthwise 3x3 bf16, normal output [c][HW].
// Tile: 8 output rows x 160 px x 8 ch. Halo 10/8 rows = 1.25x fetch.
// grid (20, 32, NB). bstride = input batch stride (elems).
// ---------------------------------------------------------------------------
__global__ __launch_bounds__(256) void dwK_k(
    const unsigned short* __restrict__ A, const float* __restrict__ w,
    unsigned short* __restrict__ out, long bstride)
{
    __shared__ unsigned short xsh[8][10][168];
    const int t = threadIdx.x;
    const int y0 = blockIdx.x * 8;
    const int c0 = blockIdx.y * 8;
    const long b = blockIdx.z;
    const unsigned short* Ab = A + b * bstride;

    for (int idx = t; idx < 1600; idx += 256) {
        int seg = idx % 20;
        int row = (idx / 20) % 10;
        int ch  = idx / 200;
        int yy  = y0 + row - 1;
        us8 v = (us8){0, 0, 0, 0, 0, 0, 0, 0};
        if (yy >= 0 && yy < IMGW)
            v = *(const us8*)(Ab + (long)(c0 + ch) * HW + yy * IMGW + seg * 8);
        *(us8*)&xsh[ch][row][seg * 8] = v;
    }
    __syncthreads();

    const int ch = t >> 5;
    const int rem = t & 31;
    const int ro = rem >> 2;
    const int xq = rem & 3;
    float wreg[9];
#pragma unroll
    for (int u = 0; u < 9; ++u) wreg[u] = w[(c0 + ch) * 9 + u];
    unsigned short* ob = out + b * SZB + (long)(c0 + ch) * HW + (y0 + ro) * IMGW;

#pragma unroll
    for (int xs = 0; xs < 5; ++xs) {
        int x = xq * 8 + xs * 32;
        float s[8];
#pragma unroll
        for (int p = 0; p < 8; ++p) s[p] = 0.f;
#pragma unroll
        for (int dy = 0; dy < 3; ++dy) {
            const unsigned short* rp = &xsh[ch][ro + dy][0];
            float r[10];
            r[0] = (x > 0) ? bf2f(rp[x - 1]) : 0.f;
            us8 mid = *(const us8*)&rp[x];
#pragma unroll
            for (int u = 0; u < 8; ++u) r[1 + u] = bf2f(mid[u]);
            r[9] = (x + 8 < IMGW) ? bf2f(rp[x + 8]) : 0.f;
            float w0 = wreg[dy * 3], w1 = wreg[dy * 3 + 1], w2 = wreg[dy * 3 + 2];
#pragma unroll
            for (int p = 0; p < 8; ++p)
                s[p] = fmaf(w0, r[p], fmaf(w1, r[p + 1], fmaf(w2, r[p + 2], s[p])));
        }
        us8 o;
#pragma unroll
        for (int p = 0; p < 8; ++p) o[p] = f2bf(s[p]);
        *(us8*)(ob + x) = o;
    }
}

// ---------------------------------------------------------------------------
// depthwise 3x3 bf16, PLAIN-transposed output VT[n][256] (for final GEMM).
// Tile: 4 output rows x 160 px x 16 ch. grid (40, 16, NB).
// ---------------------------------------------------------------------------
__global__ __launch_bounds__(256) void dwV_k(
    const unsigned short* __restrict__ A, const float* __restrict__ w,
    unsigned short* __restrict__ out, long bstride)
{
    __shared__ unsigned short xsh[16][6][168];
    __shared__ unsigned short osh[640][17];
    const int t = threadIdx.x;
    const int y0 = blockIdx.x * 4;
    const int c0 = blockIdx.y * 16;
    const long b = blockIdx.z;
    const unsigned short* Ab = A + b * bstride;

    for (int idx = t; idx < 1920; idx += 256) {
        int seg = idx % 20;
        int row = (idx / 20) % 6;
        int ch  = idx / 120;
        int yy  = y0 + row - 1;
        us8 v = (us8){0, 0, 0, 0, 0, 0, 0, 0};
        if (yy >= 0 && yy < IMGW)
            v = *(const us8*)(Ab + (long)(c0 + ch) * HW + yy * IMGW + seg * 8);
        *(us8*)&xsh[ch][row][seg * 8] = v;
    }
    __syncthreads();

    {
        const int ch = t >> 4;
        const int rem = t & 15;
        const int ro = rem >> 2;
        const int xq = rem & 3;
        float wreg[9];
#pragma unroll
        for (int u = 0; u < 9; ++u) wreg[u] = w[(c0 + ch) * 9 + u];
#pragma unroll
        for (int xs = 0; xs < 5; ++xs) {
            int x = xq * 8 + xs * 32;
            float s[8];
#pragma unroll
            for (int p = 0; p < 8; ++p) s[p] = 0.f;
#pragma unroll
            for (int dy = 0; dy < 3; ++dy) {
                const unsigned short* rp = &xsh[ch][ro + dy][0];
                float r[10];
                r[0] = (x > 0) ? bf2f(rp[x - 1]) : 0.f;
                us8 mid = *(const us8*)&rp[x];
#pragma unroll
                for (int u = 0; u < 8; ++u) r[1 + u] = bf2f(mid[u]);
                r[9] = (x + 8 < IMGW) ? bf2f(rp[x + 8]) : 0.f;
                float w0 = wreg[dy * 3], w1 = wreg[dy * 3 + 1], w2 = wreg[dy * 3 + 2];
#pragma unroll
                for (int p = 0; p < 8; ++p)
                    s[p] = fmaf(w0, r[p], fmaf(w1, r[p + 1], fmaf(w2, r[p + 2], s[p])));
            }
            int nl = ro * IMGW + x;
#pragma unroll
            for (int p = 0; p < 8; ++p) osh[nl + p][ch] = f2bf(s[p]);
        }
    }
    __syncthreads();

    for (int idx = t; idx < 1280; idx += 256) {
        int nl = idx >> 1;
        int c8 = (idx & 1) * 8;
        us8 o;
#pragma unroll
        for (int u = 0; u < 8; ++u) o[u] = osh[nl][c8 + u];
        long n = y0 * IMGW + nl;
        *(us8*)(out + b * SZB + n * CDIM + c0 + c8) = o;
    }
}

// ---------------------------------------------------------------------------
// gram via MFMA, direct global us8 frag loads (same k-slot map both operands).
// grid (8 chunks, 8 heads, NB)
// ---------------------------------------------------------------------------
__global__ __launch_bounds__(256) void gram_k(
    const unsigned short* __restrict__ q, const unsigned short* __restrict__ k,
    float* __restrict__ part_qk, float* __restrict__ part_sq_q,
    float* __restrict__ part_sq_k)
{
    __shared__ float Sred[4 * 1024];
    __shared__ float sqq_l[4][32];
    __shared__ float sqk_l[4][32];
    const int t  = threadIdx.x;
    const int l  = t & 63;
    const int wv = t >> 6;
    const int g  = l >> 4;
    const int ln = l & 15;
    const int chunk = blockIdx.x;
    const int h = blockIdx.y;
    const int b = blockIdx.z;

    f32x4 accS[2][2], accQ[2], accK[2];
#pragma unroll
    for (int i = 0; i < 2; ++i) {
        accQ[i] = (f32x4){0, 0, 0, 0};
        accK[i] = (f32x4){0, 0, 0, 0};
#pragma unroll
        for (int j = 0; j < 2; ++j) accS[i][j] = (f32x4){0, 0, 0, 0};
    }

    const unsigned short* qb = q + (long)b * SZB + (long)(h * 32) * HW;
    const unsigned short* kb = k + (long)b * SZB + (long)(h * 32) * HW;
    long nb = (long)chunk * 3200 + wv * 800;
    for (int s = 0; s < 25; ++s, nb += 32) {
        FragU aq[2], bk[2];
#pragma unroll
        for (int i = 0; i < 2; ++i)
            aq[i].o = *(const us8*)(qb + (long)(i * 16 + ln) * HW + nb + g * 8);
#pragma unroll
        for (int j = 0; j < 2; ++j)
            bk[j].o = *(const us8*)(kb + (long)(j * 16 + ln) * HW + nb + g * 8);
#pragma unroll
        for (int i = 0; i < 2; ++i)
#pragma unroll
            for (int j = 0; j < 2; ++j)
                accS[i][j] = __builtin_amdgcn_mfma_f32_16x16x32_bf16(
                    aq[i].s, bk[j].s, accS[i][j], 0, 0, 0);
#pragma unroll
        for (int i = 0; i < 2; ++i) {
            accQ[i] = __builtin_amdgcn_mfma_f32_16x16x32_bf16(
                aq[i].s, aq[i].s, accQ[i], 0, 0, 0);
            accK[i] = __builtin_amdgcn_mfma_f32_16x16x32_bf16(
                bk[i].s, bk[i].s, accK[i], 0, 0, 0);
        }
    }
#pragma unroll
    for (int i = 0; i < 2; ++i)
#pragma unroll
        for (int j = 0; j < 2; ++j)
#pragma unroll
            for (int r = 0; r < 4; ++r) {
                int row = i * 16 + g * 4 + r;
                int col = j * 16 + ln;
                Sred[wv * 1024 + row * 32 + col] = accS[i][j][r];
            }
#pragma unroll
    for (int i = 0; i < 2; ++i)
#pragma unroll
        for (int r = 0; r < 4; ++r)
            if (ln == g * 4 + r) {
                sqq_l[wv][i * 16 + g * 4 + r] = accQ[i][r];
                sqk_l[wv][i * 16 + g * 4 + r] = accK[i][r];
            }
    __syncthreads();
    const long pb = ((long)(b * NHEADS + h) * 8 + chunk);
#pragma unroll
    for (int e0 = 0; e0 < 4; ++e0) {
        int e = e0 * 256 + t;
        float v = Sred[e] + Sred[1024 + e] + Sred[2048 + e] + Sred[3072 + e];
        part_qk[pb * 1024 + e] = v;
    }
    if (t < 32)
        part_sq_q[pb * 32 + t] = sqq_l[0][t] + sqq_l[1][t] + sqq_l[2][t] + sqq_l[3][t];
    else if (t < 64) {
        int j = t - 32;
        part_sq_k[pb * 32 + j] = sqk_l[0][j] + sqk_l[1][j] + sqk_l[2][j] + sqk_l[3][j];
    }
}

// ---------------------------------------------------------------------------
// reduce -> normalize -> softmax -> W_eff = proj_w @ blockdiag(attn),
// stored PLAIN [b][co][256]. grid 32 = (b,h)
// ---------------------------------------------------------------------------
__global__ __launch_bounds__(256) void attn_weff_k(
    const float* __restrict__ part_qk, const float* __restrict__ part_sq_q,
    const float* __restrict__ part_sq_k, const float* __restrict__ proj_w,
    const float* __restrict__ temp, unsigned short* __restrict__ weff)
{
    __shared__ float at[32 * 33];
    __shared__ float nq[32], nk[32];
    int bh = blockIdx.x;
    int b = bh >> 3, h = bh & 7;
    int t = threadIdx.x;
    long pb0 = (long)bh * 8;
    float4 s = make_float4(0, 0, 0, 0);
    for (int c = 0; c < 8; ++c) {
        float4 v = *(const float4*)(part_qk + (pb0 + c) * 1024 + t * 4);
        s.x += v.x; s.y += v.y; s.z += v.z; s.w += v.w;
    }
    if (t < 32) {
        float a = 0;
        for (int c = 0; c < 8; ++c) a += part_sq_q[(pb0 + c) * 32 + t];
        nq[t] = fmaxf(sqrtf(a), 1e-12f);
    } else if (t < 64) {
        int j = t - 32;
        float a = 0;
        for (int c = 0; c < 8; ++c) a += part_sq_k[(pb0 + c) * 32 + j];
        nk[j] = fmaxf(sqrtf(a), 1e-12f);
    }
    __syncthreads();
    float tp = temp[h];
    int ci = t >> 3, cj0 = (t & 7) * 4;
    at[ci * 33 + cj0 + 0] = s.x / (nq[ci] * nk[cj0 + 0]) * tp;
    at[ci * 33 + cj0 + 1] = s.y / (nq[ci] * nk[cj0 + 1]) * tp;
    at[ci * 33 + cj0 + 2] = s.z / (nq[ci] * nk[cj0 + 2]) * tp;
    at[ci * 33 + cj0 + 3] = s.w / (nq[ci] * nk[cj0 + 3]) * tp;
    __syncthreads();
    if (t < 32) {
        float m = -1e30f;
        for (int j = 0; j < 32; ++j) m = fmaxf(m, at[t * 33 + j]);
        float ss = 0;
        for (int j = 0; j < 32; ++j) {
            float e = expf(at[t * 33 + j] - m);
            at[t * 33 + j] = e;
            ss += e;
        }
        float inv = 1.f / ss;
        for (int j = 0; j < 32; ++j) at[t * 33 + j] *= inv;
    }
    __syncthreads();
    int co = t;
    float pw[32];
#pragma unroll
    for (int i2 = 0; i2 < 32; ++i2) pw[i2] = proj_w[(long)co * CDIM + h * 32 + i2];
    unsigned short* wb = weff + (long)b * 65536 + (long)co * CDIM + h * 32;
    for (int j = 0; j < 32; ++j) {
        float a = 0;
#pragma unroll
        for (int i2 = 0; i2 < 32; ++i2) a = fmaf(pw[i2], at[i2 * 33 + j], a);
        wb[j] = f2bf(a);
    }
}

// ---------------------------------------------------------------------------
extern "C" void kernel_launch(void* const* d_in, const int* in_sizes, int n_in,
                              void* d_out, int out_size, void* d_ws, size_t ws_size,
                              hipStream_t stream)
{
    const float* low    = (const float*)d_in[0];
    const float* high   = (const float*)d_in[1];
    const float* q_w    = (const float*)d_in[2];
    const float* q_dw   = (const float*)d_in[3];
    const float* kv_w   = (const float*)d_in[4];
    const float* kv_dw  = (const float*)d_in[5];
    const float* proj_w = (const float*)d_in[6];
    const float* temp   = (const float*)d_in[7];
    float* out = (float*)d_out;

    // workspace (bf16 elems)
    unsigned short* usws = (unsigned short*)d_ws;
    unsigned short* Areg = usws;                  // [4][512][HW]   8*SZB
    unsigned short* VT   = Areg + 8 * SZB;        // [4][HW][256]   4*SZB (plain T)
    unsigned short* wkv_p = VT + 4 * SZB;         // [512][256]
    unsigned short* wq_p  = wkv_p + 131072;       // [256][256]
    unsigned short* weff_p = wq_p + 65536;        // [4][256][256]
    float* part_qk   = (float*)(weff_p + 4L * 65536);
    float* part_sq_q = part_qk + 32L * 8 * 1024;
    float* part_sq_k = part_sq_q + 32L * 8 * 32;
    float* endp      = part_sq_k + 32L * 8 * 32;
    if (ws_size < (size_t)((char*)endp - (char*)d_ws)) return;

    // d_out as scratch: K_all then Q_all (bf16), consumed before final write
    unsigned short* K_all = (unsigned short*)d_out;           // [4][256][HW]
    unsigned short* Q_all = K_all + 4 * SZB;                  // [4][256][HW]

    dim3 blk(256);

    // all weights -> plain bf16 (1 dispatch)
    cvtw_k<<<dim3(96), blk, 0, stream>>>(kv_w, q_w, wkv_p, wq_p);

    // kv chain: fused K+V GEMM straight from fp32 low
    gemm5_k<0, 1><<<dim3(4, 200, NB), blk, 0, stream>>>(
        low, wkv_p, Areg, SZB, 0, 2 * SZB);
    dwK_k<<<dim3(20, 32, NB), blk, 0, stream>>>(Areg, kv_dw, K_all, 2 * SZB);
    dwV_k<<<dim3(40, 16, NB), blk, 0, stream>>>(Areg + 256L * HW,
                                                kv_dw + 256 * 9, VT, 2 * SZB);

    // q chain (reuses Areg rows 0..255, stride 2*SZB)
    gemm5_k<0, 1><<<dim3(2, 200, NB), blk, 0, stream>>>(
        high, wq_p, Areg, SZB, 0, 2 * SZB);
    dwK_k<<<dim3(20, 32, NB), blk, 0, stream>>>(Areg, q_dw, Q_all, 2 * SZB);

    // gram + softmax + W_eff
    gram_k<<<dim3(8, NHEADS, NB), blk, 0, stream>>>(Q_all, K_all, part_qk,
                                                    part_sq_q, part_sq_k);
    attn_weff_k<<<dim3(32), blk, 0, stream>>>(
        part_qk, part_sq_q, part_sq_k, proj_w, temp, weff_p);

    // out[b] = W_eff[b] @ v[b]   (VT is plain v^T per batch)
    gemm5_k<1, 0><<<dim3(2, 200, NB), blk, 0, stream>>>(VT, weff_p, out,
                                                        SZB, 65536, SZB);
}

// Round 14
// 291.193 us; speedup vs baseline: 1.2855x; 1.2855x over previous
//
#include <hip/hip_runtime.h>
#include <math.h>

#define HW 25600
#define IMGW 160
#define CDIM 256
#define NB 4
#define NHEADS 8
#define SZB ((long)CDIM * HW)   // 6,553,600 elems

typedef __attribute__((ext_vector_type(8))) short short8v;
typedef __attribute__((ext_vector_type(4))) float f32x4;
typedef __attribute__((ext_vector_type(8))) unsigned short us8;

union FragU {
    us8 o;
    short8v s;
    unsigned u32[4];
};

__device__ inline unsigned short f2bf(float f) {
    unsigned u = __float_as_uint(f);
    return (unsigned short)((u + 0x7fffu + ((u >> 16) & 1u)) >> 16);
}
__device__ inline float bf2f(unsigned short h) {
    return __uint_as_float(((unsigned)h) << 16);
}

// ---------------------------------------------------------------------------
// weights fp32 -> FRAGMENT-ORDER bf16.
// Layout (us8 units): Wf[c][kt][l]  where c = co>>4, kt = k>>5,
// lane l = (g*16 + (co&15)), g = (k&31)>>3 -> a wave's A-frag read is one
// contiguous 1KB block: us8 index (c*8+kt)*64 + l.
// kv_w (16384 us8) then q_w (8192 us8). grid(96)
// ---------------------------------------------------------------------------
__global__ __launch_bounds__(256) void cvtw_k(
    const float* __restrict__ kv_w, const float* __restrict__ q_w,
    unsigned short* __restrict__ wkvf, unsigned short* __restrict__ wqf)
{
    int idx = blockIdx.x * 256 + threadIdx.x;   // us8 id, 0..24575
    const float* src;
    unsigned short* dst;
    int rel;
    if (idx < 16384) { src = kv_w; dst = wkvf; rel = idx; }
    else             { src = q_w;  dst = wqf;  rel = idx - 16384; }
    int l  = rel & 63;
    int kt = (rel >> 6) & 7;
    int c  = rel >> 9;
    int co = c * 16 + (l & 15);
    int k0 = kt * 32 + (l >> 4) * 8;
    const float* s = src + (long)co * CDIM + k0;
    us8 o;
#pragma unroll
    for (int u = 0; u < 8; ++u) o[u] = f2bf(s[u]);
    *(us8*)(dst + (long)rel * 8) = o;
}

// ---------------------------------------------------------------------------
// bf16 MFMA GEMM v6 -- X-stationary, barrier-free co-loop:
// out[b][co][n] = sum_k W[co][k] * X[k][n],  K=256, n-tile=128, co looped.
//  * X panel (256k x 128n) staged ONCE into 64KB LDS (bf16), slot-XOR
//    swizzle (slot ^= row&7) -> ds_read_b128 2-way free. ONE barrier total.
//  * W streamed per-frag from global in fragment-order (contiguous 1KB/wave
//    reads, L2-resident) -- no W LDS, no K-loop barriers.
//  * co-loop reuses the staged X for ncot co-tiles (KV: 4, q/final: 2).
//  * s_setprio around MFMA cluster (waves desynced -> T5 applies).
// XF32=1: X fp32 [k][HW], reg cvt_pk during staging. XF32=0: X bf16 [n][256].
// grid (HW/128, NB).
// ---------------------------------------------------------------------------
template<int OUTF32, int XF32>
__global__ __launch_bounds__(256) void gemm6_k(
    const void* __restrict__ Xv, const unsigned short* __restrict__ Wf,
    void* __restrict__ outp, long xbs, long wbs, long obs, int ncot)
{
    __shared__ __align__(16) unsigned short Xl[128 * 256];   // 64KB, swz slots
    const int t  = threadIdx.x;
    const int l  = t & 63;
    const int wv = t >> 6;
    const int g  = l >> 4;
    const int ln = l & 15;
    const int n0 = blockIdx.x * 128;
    const long b = blockIdx.y;
    const unsigned short* Wb  = Wf + b * wbs;
    const float* Xfp          = (const float*)Xv + b * xbs;
    const unsigned short* Xbf = (const unsigned short*)Xv + b * xbs;
    const int wr = wv >> 1, wc = wv & 1;

    // ---- stage X panel into LDS (one time)
    if (XF32) {
        const int n_l = t & 127;
        const int khalf = t >> 7;
#pragma unroll
        for (int kc = 0; kc < 16; ++kc) {
            int k0 = khalf * 128 + kc * 8;
            float f[8];
#pragma unroll
            for (int u = 0; u < 8; ++u)
                f[u] = Xfp[(long)(k0 + u) * HW + n0 + n_l];
            FragU cv;
#pragma unroll
            for (int e2 = 0; e2 < 4; ++e2) {
                unsigned rr;
                asm("v_cvt_pk_bf16_f32 %0, %1, %2"
                    : "=v"(rr) : "v"(f[e2 * 2]), "v"(f[e2 * 2 + 1]));
                cv.u32[e2] = rr;
            }
            int slot = (khalf * 16 + kc) ^ (n_l & 7);
            *(us8*)&Xl[n_l * 256 + slot * 8] = cv.o;
        }
    } else {
#pragma unroll
        for (int u = 0; u < 16; ++u) {
            int gi = u * 256 + t;          // coalesced: lanes consecutive us8
            int row = gi >> 5;
            int kc  = gi & 31;
            us8 v = *(const us8*)&Xbf[(long)(n0 + row) * CDIM + kc * 8];
            int slot = kc ^ (row & 7);
            *(us8*)&Xl[row * 256 + slot * 8] = v;
        }
    }
    __syncthreads();

    // ---- co-loop: zero barriers from here on
    for (int cot = 0; cot < ncot; ++cot) {
        f32x4 acc[4][4];
#pragma unroll
        for (int i = 0; i < 4; ++i)
#pragma unroll
            for (int j = 0; j < 4; ++j) acc[i][j] = (f32x4){0.f, 0.f, 0.f, 0.f};

        const int cb8 = cot * 8 + wr * 4;   // c-index base (16-row groups)
#pragma unroll
        for (int kt = 0; kt < 8; ++kt) {
            FragU A_[4], B_[4];
#pragma unroll
            for (int i = 0; i < 4; ++i)
                A_[i].o = *(const us8*)&Wb[(((long)(cb8 + i) * 8 + kt) * 64 + l) * 8];
#pragma unroll
            for (int j = 0; j < 4; ++j) {
                int row = wc * 64 + j * 16 + ln;
                int slot = (kt * 4 + g) ^ (ln & 7);
                B_[j].o = *(const us8*)&Xl[row * 256 + slot * 8];
            }
            __builtin_amdgcn_s_setprio(1);
#pragma unroll
            for (int i = 0; i < 4; ++i)
#pragma unroll
                for (int j = 0; j < 4; ++j)
                    acc[i][j] = __builtin_amdgcn_mfma_f32_16x16x32_bf16(
                        A_[i].s, B_[j].s, acc[i][j], 0, 0, 0);
            __builtin_amdgcn_s_setprio(0);
        }

        // epilogue: direct stores (L2 write-back merges 32B segments)
        // D layout: col=lane&15, row=(lane>>4)*4+reg (HW-verified)
        if (OUTF32) {
            float* ob = (float*)outp + b * obs;
#pragma unroll
            for (int i = 0; i < 4; ++i)
#pragma unroll
                for (int j = 0; j < 4; ++j) {
                    long ocol = n0 + wc * 64 + j * 16 + ln;
#pragma unroll
                    for (int r = 0; r < 4; ++r) {
                        long orow = cot * 128 + wr * 64 + i * 16 + g * 4 + r;
                        ob[orow * HW + ocol] = acc[i][j][r];
                    }
                }
        } else {
            unsigned short* ob = (unsigned short*)outp + b * obs;
#pragma unroll
            for (int i = 0; i < 4; ++i)
#pragma unroll
                for (int j = 0; j < 4; ++j) {
                    long ocol = n0 + wc * 64 + j * 16 + ln;
#pragma unroll
                    for (int r = 0; r < 4; ++r) {
                        long orow = cot * 128 + wr * 64 + i * 16 + g * 4 + r;
                        ob[orow * HW + ocol] = f2bf(acc[i][j][r]);
                    }
                }
        }
    }
}

// ---------------------------------------------------------------------------
// depthwise 3x3 bf16, normal output [c][HW].
// Tile: 8 output rows x 160 px x 8 ch. Halo 1.25x. grid (20, 32, NB).
// ---------------------------------------------------------------------------
__global__ __launch_bounds__(256) void dwK_k(
    const unsigned short* __restrict__ A, const float* __restrict__ w,
    unsigned short* __restrict__ out, long bstride)
{
    __shared__ unsigned short xsh[8][10][168];
    const int t = threadIdx.x;
    const int y0 = blockIdx.x * 8;
    const int c0 = blockIdx.y * 8;
    const long b = blockIdx.z;
    const unsigned short* Ab = A + b * bstride;

    for (int idx = t; idx < 1600; idx += 256) {
        int seg = idx % 20;
        int row = (idx / 20) % 10;
        int ch  = idx / 200;
        int yy  = y0 + row - 1;
        us8 v = (us8){0, 0, 0, 0, 0, 0, 0, 0};
        if (yy >= 0 && yy < IMGW)
            v = *(const us8*)(Ab + (long)(c0 + ch) * HW + yy * IMGW + seg * 8);
        *(us8*)&xsh[ch][row][seg * 8] = v;
    }
    __syncthreads();

    const int ch = t >> 5;
    const int rem = t & 31;
    const int ro = rem >> 2;
    const int xq = rem & 3;
    float wreg[9];
#pragma unroll
    for (int u = 0; u < 9; ++u) wreg[u] = w[(c0 + ch) * 9 + u];
    unsigned short* ob = out + b * SZB + (long)(c0 + ch) * HW + (y0 + ro) * IMGW;

#pragma unroll
    for (int xs = 0; xs < 5; ++xs) {
        int x = xq * 8 + xs * 32;
        float s[8];
#pragma unroll
        for (int p = 0; p < 8; ++p) s[p] = 0.f;
#pragma unroll
        for (int dy = 0; dy < 3; ++dy) {
            const unsigned short* rp = &xsh[ch][ro + dy][0];
            float r[10];
            r[0] = (x > 0) ? bf2f(rp[x - 1]) : 0.f;
            us8 mid = *(const us8*)&rp[x];
#pragma unroll
            for (int u = 0; u < 8; ++u) r[1 + u] = bf2f(mid[u]);
            r[9] = (x + 8 < IMGW) ? bf2f(rp[x + 8]) : 0.f;
            float w0 = wreg[dy * 3], w1 = wreg[dy * 3 + 1], w2 = wreg[dy * 3 + 2];
#pragma unroll
            for (int p = 0; p < 8; ++p)
                s[p] = fmaf(w0, r[p], fmaf(w1, r[p + 1], fmaf(w2, r[p + 2], s[p])));
        }
        us8 o;
#pragma unroll
        for (int p = 0; p < 8; ++p) o[p] = f2bf(s[p]);
        *(us8*)(ob + x) = o;
    }
}

// ---------------------------------------------------------------------------
// depthwise 3x3 bf16, PLAIN-transposed output VT[n][256] (for final GEMM).
// Tile: 4 output rows x 160 px x 16 ch. grid (40, 16, NB).
// ---------------------------------------------------------------------------
__global__ __launch_bounds__(256) void dwV_k(
    const unsigned short* __restrict__ A, const float* __restrict__ w,
    unsigned short* __restrict__ out, long bstride)
{
    __shared__ unsigned short xsh[16][6][168];
    __shared__ unsigned short osh[640][17];
    const int t = threadIdx.x;
    const int y0 = blockIdx.x * 4;
    const int c0 = blockIdx.y * 16;
    const long b = blockIdx.z;
    const unsigned short* Ab = A + b * bstride;

    for (int idx = t; idx < 1920; idx += 256) {
        int seg = idx % 20;
        int row = (idx / 20) % 6;
        int ch  = idx / 120;
        int yy  = y0 + row - 1;
        us8 v = (us8){0, 0, 0, 0, 0, 0, 0, 0};
        if (yy >= 0 && yy < IMGW)
            v = *(const us8*)(Ab + (long)(c0 + ch) * HW + yy * IMGW + seg * 8);
        *(us8*)&xsh[ch][row][seg * 8] = v;
    }
    __syncthreads();

    {
        const int ch = t >> 4;
        const int rem = t & 15;
        const int ro = rem >> 2;
        const int xq = rem & 3;
        float wreg[9];
#pragma unroll
        for (int u = 0; u < 9; ++u) wreg[u] = w[(c0 + ch) * 9 + u];
#pragma unroll
        for (int xs = 0; xs < 5; ++xs) {
            int x = xq * 8 + xs * 32;
            float s[8];
#pragma unroll
            for (int p = 0; p < 8; ++p) s[p] = 0.f;
#pragma unroll
            for (int dy = 0; dy < 3; ++dy) {
                const unsigned short* rp = &xsh[ch][ro + dy][0];
                float r[10];
                r[0] = (x > 0) ? bf2f(rp[x - 1]) : 0.f;
                us8 mid = *(const us8*)&rp[x];
#pragma unroll
                for (int u = 0; u < 8; ++u) r[1 + u] = bf2f(mid[u]);
                r[9] = (x + 8 < IMGW) ? bf2f(rp[x + 8]) : 0.f;
                float w0 = wreg[dy * 3], w1 = wreg[dy * 3 + 1], w2 = wreg[dy * 3 + 2];
#pragma unroll
                for (int p = 0; p < 8; ++p)
                    s[p] = fmaf(w0, r[p], fmaf(w1, r[p + 1], fmaf(w2, r[p + 2], s[p])));
            }
            int nl = ro * IMGW + x;
#pragma unroll
            for (int p = 0; p < 8; ++p) osh[nl + p][ch] = f2bf(s[p]);
        }
    }
    __syncthreads();

    for (int idx = t; idx < 1280; idx += 256) {
        int nl = idx >> 1;
        int c8 = (idx & 1) * 8;
        us8 o;
#pragma unroll
        for (int u = 0; u < 8; ++u) o[u] = osh[nl][c8 + u];
        long n = y0 * IMGW + nl;
        *(us8*)(out + b * SZB + n * CDIM + c0 + c8) = o;
    }
}

// ---------------------------------------------------------------------------
// gram via MFMA, direct global us8 frag loads (same k-slot map both operands).
// grid (8 chunks, 8 heads, NB)
// ---------------------------------------------------------------------------
__global__ __launch_bounds__(256) void gram_k(
    const unsigned short* __restrict__ q, const unsigned short* __restrict__ k,
    float* __restrict__ part_qk, float* __restrict__ part_sq_q,
    float* __restrict__ part_sq_k)
{
    __shared__ float Sred[4 * 1024];
    __shared__ float sqq_l[4][32];
    __shared__ float sqk_l[4][32];
    const int t  = threadIdx.x;
    const int l  = t & 63;
    const int wv = t >> 6;
    const int g  = l >> 4;
    const int ln = l & 15;
    const int chunk = blockIdx.x;
    const int h = blockIdx.y;
    const int b = blockIdx.z;

    f32x4 accS[2][2], accQ[2], accK[2];
#pragma unroll
    for (int i = 0; i < 2; ++i) {
        accQ[i] = (f32x4){0, 0, 0, 0};
        accK[i] = (f32x4){0, 0, 0, 0};
#pragma unroll
        for (int j = 0; j < 2; ++j) accS[i][j] = (f32x4){0, 0, 0, 0};
    }

    const unsigned short* qb = q + (long)b * SZB + (long)(h * 32) * HW;
    const unsigned short* kb = k + (long)b * SZB + (long)(h * 32) * HW;
    long nb = (long)chunk * 3200 + wv * 800;
    for (int s = 0; s < 25; ++s, nb += 32) {
        FragU aq[2], bk[2];
#pragma unroll
        for (int i = 0; i < 2; ++i)
            aq[i].o = *(const us8*)(qb + (long)(i * 16 + ln) * HW + nb + g * 8);
#pragma unroll
        for (int j = 0; j < 2; ++j)
            bk[j].o = *(const us8*)(kb + (long)(j * 16 + ln) * HW + nb + g * 8);
#pragma unroll
        for (int i = 0; i < 2; ++i)
#pragma unroll
            for (int j = 0; j < 2; ++j)
                accS[i][j] = __builtin_amdgcn_mfma_f32_16x16x32_bf16(
                    aq[i].s, bk[j].s, accS[i][j], 0, 0, 0);
#pragma unroll
        for (int i = 0; i < 2; ++i) {
            accQ[i] = __builtin_amdgcn_mfma_f32_16x16x32_bf16(
                aq[i].s, aq[i].s, accQ[i], 0, 0, 0);
            accK[i] = __builtin_amdgcn_mfma_f32_16x16x32_bf16(
                bk[i].s, bk[i].s, accK[i], 0, 0, 0);
        }
    }
#pragma unroll
    for (int i = 0; i < 2; ++i)
#pragma unroll
        for (int j = 0; j < 2; ++j)
#pragma unroll
            for (int r = 0; r < 4; ++r) {
                int row = i * 16 + g * 4 + r;
                int col = j * 16 + ln;
                Sred[wv * 1024 + row * 32 + col] = accS[i][j][r];
            }
#pragma unroll
    for (int i = 0; i < 2; ++i)
#pragma unroll
        for (int r = 0; r < 4; ++r)
            if (ln == g * 4 + r) {
                sqq_l[wv][i * 16 + g * 4 + r] = accQ[i][r];
                sqk_l[wv][i * 16 + g * 4 + r] = accK[i][r];
            }
    __syncthreads();
    const long pb = ((long)(b * NHEADS + h) * 8 + chunk);
#pragma unroll
    for (int e0 = 0; e0 < 4; ++e0) {
        int e = e0 * 256 + t;
        float v = Sred[e] + Sred[1024 + e] + Sred[2048 + e] + Sred[3072 + e];
        part_qk[pb * 1024 + e] = v;
    }
    if (t < 32)
        part_sq_q[pb * 32 + t] = sqq_l[0][t] + sqq_l[1][t] + sqq_l[2][t] + sqq_l[3][t];
    else if (t < 64) {
        int j = t - 32;
        part_sq_k[pb * 32 + j] = sqk_l[0][j] + sqk_l[1][j] + sqk_l[2][j] + sqk_l[3][j];
    }
}

// ---------------------------------------------------------------------------
// reduce -> normalize -> softmax -> W_eff = proj_w @ blockdiag(attn),
// stored in FRAGMENT-ORDER per batch (same layout as cvtw_k output).
// grid 32 = (b,h)
// ---------------------------------------------------------------------------
__global__ __launch_bounds__(256) void attn_weff_k(
    const float* __restrict__ part_qk, const float* __restrict__ part_sq_q,
    const float* __restrict__ part_sq_k, const float* __restrict__ proj_w,
    const float* __restrict__ temp, unsigned short* __restrict__ wefff)
{
    __shared__ float at[32 * 33];
    __shared__ float nq[32], nk[32];
    int bh = blockIdx.x;
    int b = bh >> 3, h = bh & 7;
    int t = threadIdx.x;
    long pb0 = (long)bh * 8;
    float4 s = make_float4(0, 0, 0, 0);
    for (int c = 0; c < 8; ++c) {
        float4 v = *(const float4*)(part_qk + (pb0 + c) * 1024 + t * 4);
        s.x += v.x; s.y += v.y; s.z += v.z; s.w += v.w;
    }
    if (t < 32) {
        float a = 0;
        for (int c = 0; c < 8; ++c) a += part_sq_q[(pb0 + c) * 32 + t];
        nq[t] = fmaxf(sqrtf(a), 1e-12f);
    } else if (t < 64) {
        int j = t - 32;
        float a = 0;
        for (int c = 0; c < 8; ++c) a += part_sq_k[(pb0 + c) * 32 + j];
        nk[j] = fmaxf(sqrtf(a), 1e-12f);
    }
    __syncthreads();
    float tp = temp[h];
    int ci = t >> 3, cj0 = (t & 7) * 4;
    at[ci * 33 + cj0 + 0] = s.x / (nq[ci] * nk[cj0 + 0]) * tp;
    at[ci * 33 + cj0 + 1] = s.y / (nq[ci] * nk[cj0 + 1]) * tp;
    at[ci * 33 + cj0 + 2] = s.z / (nq[ci] * nk[cj0 + 2]) * tp;
    at[ci * 33 + cj0 + 3] = s.w / (nq[ci] * nk[cj0 + 3]) * tp;
    __syncthreads();
    if (t < 32) {
        float m = -1e30f;
        for (int j = 0; j < 32; ++j) m = fmaxf(m, at[t * 33 + j]);
        float ss = 0;
        for (int j = 0; j < 32; ++j) {
            float e = expf(at[t * 33 + j] - m);
            at[t * 33 + j] = e;
            ss += e;
        }
        float inv = 1.f / ss;
        for (int j = 0; j < 32; ++j) at[t * 33 + j] *= inv;
    }
    __syncthreads();
    int co = t;
    float pw[32];
#pragma unroll
    for (int i2 = 0; i2 < 32; ++i2) pw[i2] = proj_w[(long)co * CDIM + h * 32 + i2];
    // fragment-order write: k = h*32+j -> kt=h, g=j>>3, e=j&7,
    // lane = g*16 + (co&15), us8 idx = ((co>>4)*8 + h)*64 + lane
    unsigned short* wb = wefff + (long)b * 65536;
    int chi = co >> 4, lr = co & 15;
    for (int j = 0; j < 32; ++j) {
        float a = 0;
#pragma unroll
        for (int i2 = 0; i2 < 32; ++i2) a = fmaf(pw[i2], at[i2 * 33 + j], a);
        int g2 = j >> 3, e = j & 7;
        long idx = ((long)(chi * 8 + h) * 64 + g2 * 16 + lr) * 8 + e;
        wb[idx] = f2bf(a);
    }
}

// ---------------------------------------------------------------------------
extern "C" void kernel_launch(void* const* d_in, const int* in_sizes, int n_in,
                              void* d_out, int out_size, void* d_ws, size_t ws_size,
                              hipStream_t stream)
{
    const float* low    = (const float*)d_in[0];
    const float* high   = (const float*)d_in[1];
    const float* q_w    = (const float*)d_in[2];
    const float* q_dw   = (const float*)d_in[3];
    const float* kv_w   = (const float*)d_in[4];
    const float* kv_dw  = (const float*)d_in[5];
    const float* proj_w = (const float*)d_in[6];
    const float* temp   = (const float*)d_in[7];
    float* out = (float*)d_out;

    // workspace (bf16 elems)
    unsigned short* usws = (unsigned short*)d_ws;
    unsigned short* Areg = usws;                  // [4][512][HW]   8*SZB
    unsigned short* VT   = Areg + 8 * SZB;        // [4][HW][256]   4*SZB (plain T)
    unsigned short* wkvf = VT + 4 * SZB;          // frag-order [32][8][64][8]
    unsigned short* wqf  = wkvf + 131072;         // frag-order [16][8][64][8]
    unsigned short* wefff = wqf + 65536;          // [4] x frag-order
    float* part_qk   = (float*)(wefff + 4L * 65536);
    float* part_sq_q = part_qk + 32L * 8 * 1024;
    float* part_sq_k = part_sq_q + 32L * 8 * 32;
    float* endp      = part_sq_k + 32L * 8 * 32;
    if (ws_size < (size_t)((char*)endp - (char*)d_ws)) return;

    // d_out as scratch: K_all then Q_all (bf16), consumed before final write
    unsigned short* K_all = (unsigned short*)d_out;           // [4][256][HW]
    unsigned short* Q_all = K_all + 4 * SZB;                  // [4][256][HW]

    dim3 blk(256);

    // weights -> fragment-order bf16 (1 dispatch)
    cvtw_k<<<dim3(96), blk, 0, stream>>>(kv_w, q_w, wkvf, wqf);

    // kv chain: fused K+V GEMM (co-loop 4) straight from fp32 low
    gemm6_k<0, 1><<<dim3(200, NB), blk, 0, stream>>>(
        low, wkvf, Areg, SZB, 0, 2 * SZB, 4);
    dwK_k<<<dim3(20, 32, NB), blk, 0, stream>>>(Areg, kv_dw, K_all, 2 * SZB);
    dwV_k<<<dim3(40, 16, NB), blk, 0, stream>>>(Areg + 256L * HW,
                                                kv_dw + 256 * 9, VT, 2 * SZB);

    // q chain (co-loop 2; writes Areg rows 0..255, stride 2*SZB)
    gemm6_k<0, 1><<<dim3(200, NB), blk, 0, stream>>>(
        high, wqf, Areg, SZB, 0, 2 * SZB, 2);
    dwK_k<<<dim3(20, 32, NB), blk, 0, stream>>>(Areg, q_dw, Q_all, 2 * SZB);

    // gram + softmax + W_eff (fragment-order)
    gram_k<<<dim3(8, NHEADS, NB), blk, 0, stream>>>(Q_all, K_all, part_qk,
                                                    part_sq_q, part_sq_k);
    attn_weff_k<<<dim3(32), blk, 0, stream>>>(
        part_qk, part_sq_q, part_sq_k, proj_w, temp, wefff);

    // out[b] = W_eff[b] @ v[b]  (VT plain v^T; co-loop 2, fp32 out)
    gemm6_k<1, 0><<<dim3(200, NB), blk, 0, stream>>>(
        VT, wefff, out, SZB, 65536, SZB, 2);
}